// Round 2
// baseline (767.237 us; speedup 1.0000x reference)
//
#include <hip/hip_runtime.h>
#include <hip/hip_bf16.h>

// ArcMarginProduct: out[b,c] = S * (c==label[b] ? phi : cos)
//   cos = <input_b/||input_b||, weight_c/||weight_c||>
//   phi = cos*cos(m) - sin*sin(m), fallback cos - S*sin(m)*m if cos <= cos(pi-m)
// B=1024, D=512, C=100000. fp32 in/out; bf16 MFMA inside (error << 0.36 threshold).

#define MDIM 1024
#define KDIM 512
#define NCLS 100000

#define BM 128
#define BN 128
#define BK 32
#define LDST 40   // LDS row stride in bf16 elems: 32 + 8 pad (80 B, breaks bank conflicts, keeps 16B align)

typedef unsigned short u16;
typedef unsigned int u32;
typedef short s16x8 __attribute__((ext_vector_type(8)));
typedef float f32x4 __attribute__((ext_vector_type(4)));

// round-to-nearest-even fp32 -> bf16, two values packed into a u32
// (manual: __hip_bfloat162 is not trivially copyable -> no bit_cast)
__device__ __forceinline__ u32 pk2(float a, float b) {
  u32 ua = __builtin_bit_cast(u32, a);
  u32 ub = __builtin_bit_cast(u32, b);
  ua += 0x7FFFu + ((ua >> 16) & 1u);
  ub += 0x7FFFu + ((ub >> 16) & 1u);
  return (ua >> 16) | (ub & 0xFFFF0000u);
}

// ---- Kernel 1: L2-normalize input rows, store bf16 row-major [1024][512] in ws ----
__global__ __launch_bounds__(256) void norm_input_kernel(const float* __restrict__ in,
                                                         u16* __restrict__ abf) {
  const int row = blockIdx.x;
  const int tid = threadIdx.x;
  const float2 v = *reinterpret_cast<const float2*>(in + (size_t)row * KDIM + 2 * tid);
  float ss = v.x * v.x + v.y * v.y;
#pragma unroll
  for (int off = 32; off > 0; off >>= 1) ss += __shfl_down(ss, off);
  __shared__ float part[4];
  if ((tid & 63) == 0) part[tid >> 6] = ss;
  __syncthreads();
  const float tot = part[0] + part[1] + part[2] + part[3];
  const float rn = 1.0f / fmaxf(sqrtf(tot), 1e-12f);  // F.normalize: x / max(||x||, eps)
  reinterpret_cast<u32*>(abf)[row * (KDIM / 2) + tid] = pk2(v.x * rn, v.y * rn);
}

// ---- Kernel 2: C = Anorm * W^T with fused weight-norm + ArcFace epilogue ----
// 128x128 tile / block, 256 threads = 4 waves in 2x2, each wave 64x64 via 4x4 of 16x16x32 MFMA.
__global__ __launch_bounds__(256) void arcface_gemm(const u16* __restrict__ Abf,
                                                    const float* __restrict__ W,
                                                    const int* __restrict__ label,
                                                    float* __restrict__ out) {
  __shared__ u16 lA[BM * LDST];
  __shared__ u16 lW[BN * LDST];
  __shared__ float rnw[BN];
  __shared__ int lbl[BM];

  const int tid = threadIdx.x;
  const int m0 = blockIdx.x * BM;          // x fastest -> sibling M-blocks share the W tile (LLC reuse)
  const int n0 = blockIdx.y * BN;

  if (tid < BM) lbl[tid] = label[m0 + tid];

  // staging assignment: thread t handles tile row r = t>>1, 16-elem half h = t&1
  const int r = tid >> 1;
  const int half = tid & 1;
  int c = n0 + r;
  if (c >= NCLS) c = NCLS - 1;  // clamp loads on the last (partial) N-tile; stores are guarded

  const u16* aptr = Abf + (size_t)(m0 + r) * KDIM + half * 16;
  const float* wptr = W + (size_t)c * KDIM + half * 16;

  // register prefetch of K-chunk 0
  uint4 a0 = *(const uint4*)(aptr);
  uint4 a1 = *(const uint4*)(aptr + 8);
  float4 w0 = *(const float4*)(wptr);
  float4 w1 = *(const float4*)(wptr + 4);
  float4 w2 = *(const float4*)(wptr + 8);
  float4 w3 = *(const float4*)(wptr + 12);

  f32x4 acc[4][4] = {};
  float ss = 0.0f;

  const int lane = tid & 63;
  const int wv = tid >> 6;
  const int wm = (wv & 1) * 64;
  const int wn = (wv >> 1) * 64;
  const int ln = lane & 15;   // MFMA: col for B/D, row for A
  const int kq = lane >> 4;   // quad: k-slice for A/B frags, row-group for C/D

  const int aw = r * LDST + half * 16;  // LDS write index (elems)

  for (int kt = 0; kt < KDIM / BK; ++kt) {
    __syncthreads();  // previous iter's frag reads done
    // stage A (already bf16)
    *(uint4*)&lA[aw] = a0;
    *(uint4*)&lA[aw + 8] = a1;
    // stage W: fp32 -> bf16, fused sum-of-squares for the row norm
    ss += w0.x * w0.x + w0.y * w0.y + w0.z * w0.z + w0.w * w0.w;
    ss += w1.x * w1.x + w1.y * w1.y + w1.z * w1.z + w1.w * w1.w;
    ss += w2.x * w2.x + w2.y * w2.y + w2.z * w2.z + w2.w * w2.w;
    ss += w3.x * w3.x + w3.y * w3.y + w3.z * w3.z + w3.w * w3.w;
    uint4 p0, p1;
    p0.x = pk2(w0.x, w0.y); p0.y = pk2(w0.z, w0.w);
    p0.z = pk2(w1.x, w1.y); p0.w = pk2(w1.z, w1.w);
    p1.x = pk2(w2.x, w2.y); p1.y = pk2(w2.z, w2.w);
    p1.z = pk2(w3.x, w3.y); p1.w = pk2(w3.z, w3.w);
    *(uint4*)&lW[aw] = p0;
    *(uint4*)&lW[aw + 8] = p1;
    __syncthreads();

    // prefetch next K-chunk into regs (issues before/under the MFMA block)
    if (kt < KDIM / BK - 1) {
      const u16* ap = aptr + (kt + 1) * BK;
      a0 = *(const uint4*)(ap);
      a1 = *(const uint4*)(ap + 8);
      const float* wp = wptr + (kt + 1) * BK;
      w0 = *(const float4*)(wp);
      w1 = *(const float4*)(wp + 4);
      w2 = *(const float4*)(wp + 8);
      w3 = *(const float4*)(wp + 12);
    }

    // fragment loads (ds_read_b128): lane ln -> row, kq*8 -> k-slice of the 32-wide chunk
    s16x8 af[4], wf[4];
#pragma unroll
    for (int i = 0; i < 4; ++i)
      af[i] = *(const s16x8*)&lA[(wm + 16 * i + ln) * LDST + kq * 8];
#pragma unroll
    for (int j = 0; j < 4; ++j)
      wf[j] = *(const s16x8*)&lW[(wn + 16 * j + ln) * LDST + kq * 8];
#pragma unroll
    for (int i = 0; i < 4; ++i)
#pragma unroll
      for (int j = 0; j < 4; ++j)
        acc[i][j] = __builtin_amdgcn_mfma_f32_16x16x32_bf16(af[i], wf[j], acc[i][j], 0, 0, 0);
  }

  // finish per-row weight norms: pair (2r, 2r+1) each hold half the k range
  const float sst = ss + __shfl_xor(ss, 1);
  if (half == 0) rnw[r] = 1.0f / fmaxf(sqrtf(sst), 1e-12f);
  __syncthreads();

  // epilogue: C/D layout col = lane&15, row = (lane>>4)*4 + reg  [verified m89/m91]
  constexpr float S_ = 30.0f;
  constexpr float COS_M = 0.87758256189037276f;
  constexpr float SIN_M = 0.47942553860420301f;
  constexpr float TH_ = -0.87758256189037276f;       // cos(pi - 0.5)
  constexpr float FALLB = 30.0f * 0.47942553860420301f * 0.5f;  // S*sin(m)*m

#pragma unroll
  for (int i = 0; i < 4; ++i) {
    const int lrow_b = wm + 16 * i + 4 * kq;
#pragma unroll
    for (int j = 0; j < 4; ++j) {
      const int col = wn + 16 * j + ln;
      const int gcol = n0 + col;
      const float rw = rnw[col];
      if (gcol < NCLS) {
#pragma unroll
        for (int rg = 0; rg < 4; ++rg) {
          const int lrow = lrow_b + rg;
          const float cosv = acc[i][j][rg] * rw;
          float o = S_ * cosv;
          if (gcol == lbl[lrow]) {
            const float s2 = fmaxf(1.0f - cosv * cosv, 0.0f);
            const float sine = sqrtf(s2);
            float phi = cosv * COS_M - sine * SIN_M;
            phi = (cosv > TH_) ? phi : (cosv - FALLB);
            o = S_ * phi;
          }
          out[(size_t)(m0 + lrow) * NCLS + gcol] = o;
        }
      }
    }
  }
}

extern "C" void kernel_launch(void* const* d_in, const int* in_sizes, int n_in,
                              void* d_out, int out_size, void* d_ws, size_t ws_size,
                              hipStream_t stream) {
  const float* input = (const float*)d_in[0];
  const int* label = (const int*)d_in[1];
  const float* weight = (const float*)d_in[2];
  float* out = (float*)d_out;
  u16* abf = (u16*)d_ws;  // 1024*512 bf16 = 1 MB normalized input

  hipLaunchKernelGGL(norm_input_kernel, dim3(MDIM), dim3(256), 0, stream, input, abf);
  dim3 grid(MDIM / BM, (NCLS + BN - 1) / BN);  // x fastest: sibling M-blocks adjacent
  hipLaunchKernelGGL(arcface_gemm, grid, dim3(256), 0, stream, abf, weight, label, out);
}